// Round 2
// baseline (10398.064 us; speedup 1.0000x reference)
//
#include <hip/hip_runtime.h>

typedef unsigned short u16;
typedef unsigned int u32;
typedef unsigned long long u64;
typedef __attribute__((ext_vector_type(8))) short short8;
typedef __attribute__((ext_vector_type(4))) float floatx4;
typedef __attribute__((ext_vector_type(4))) u32 u32x4;

#define B_   256
#define T_   512
#define E_   512
#define H_   1024
#define G4H  4096
#define KCAT 1536
#define M_   1024

__device__ __forceinline__ u16 f2bf(float f) {
    union { float f; unsigned u; } v; v.f = f;
    unsigned r = (v.u + 0x7fffu + ((v.u >> 16) & 1u)) >> 16;
    return (u16)r;
}
__device__ __forceinline__ float sigf(float x) {
    return __fdividef(1.0f, 1.0f + __expf(-x));
}
__device__ __forceinline__ float tanh_f(float x) {
    return 1.0f - __fdividef(2.0f, __expf(2.0f * x) + 1.0f);
}
// device-coherent 16B load (bypass L1/L2 -> always fresh at MALL), imm offset
__device__ __forceinline__ u32x4 load_sc(const u16* p, int imm) {
    u32x4 r;
    asm volatile("global_load_dwordx4 %0, %1, off offset:%2 sc0 sc1"
                 : "=v"(r) : "v"(p), "i"(imm) : "memory");
    return r;
}
// plain cached 16B load via asm (so manual vmcnt accounting stays exact)
__device__ __forceinline__ u32x4 load_g(const u16* p, int imm) {
    u32x4 r;
    asm volatile("global_load_dwordx4 %0, %1, off offset:%2"
                 : "=v"(r) : "v"(p), "i"(imm) : "memory");
    return r;
}
__device__ __forceinline__ short8 as_s8(u32x4 v) {
    union { u32x4 u; short8 s; } x; x.u = v; return x.s;
}

// ---------------- prep kernels ----------------

// rank rows by x_index descending (stable): perm[rank]=orig, sxi[rank]=xi
__global__ void sort_rows(const int* __restrict__ x_index,
                          int* __restrict__ perm, int* __restrict__ sxi) {
    __shared__ int xl[B_];
    int tid = threadIdx.x;
    xl[tid] = x_index[tid];
    __syncthreads();
    int mine = xl[tid], rank = 0;
    for (int j = 0; j < B_; ++j)
        rank += (xl[j] > mine) || (xl[j] == mine && j < tid);
    perm[rank] = tid;
    sxi[rank] = mine;
}

// emb_bf[srow][t][e] = bf16(tab[x[perm[srow]][t]][e])
__global__ void prep_emb(const int* __restrict__ x, const float* __restrict__ tab,
                         const int* __restrict__ perm, u16* __restrict__ emb) {
    int idx = (blockIdx.x * 256 + threadIdx.x) * 4;   // [0, B*T*E)
    int srow = idx >> 18;                             // / (T*E)
    int t    = (idx >> 9) & 511;
    int e    = idx & 511;
    int orig = perm[srow];
    int xv   = x[orig * T_ + t];
    float4 v = *(const float4*)(tab + (size_t)xv * E_ + e);
    ushort4 o; o.x = f2bf(v.x); o.y = f2bf(v.y); o.z = f2bf(v.z); o.w = f2bf(v.w);
    *(ushort4*)(emb + idx) = o;
}

__global__ void prep_wcat(const float* __restrict__ Whh, const float* __restrict__ Wih,
                          u16* __restrict__ wcat) {
    int idx = (blockIdx.x * 256 + threadIdx.x) * 4;   // [0, 4096*1536)
    int g = idx / KCAT;
    int k = idx - g * KCAT;
    const float* src = (k < H_) ? (Whh + (size_t)g * H_ + k)
                                : (Wih + (size_t)g * E_ + (k - H_));
    float4 v = *(const float4*)src;
    ushort4 o; o.x = f2bf(v.x); o.y = f2bf(v.y); o.z = f2bf(v.z); o.w = f2bf(v.w);
    *(ushort4*)(wcat + idx) = o;
}

__global__ void prep_fc1w(const float* __restrict__ src, u16* __restrict__ dst) {
    int idx = (blockIdx.x * 256 + threadIdx.x) * 4;
    float4 v = *(const float4*)(src + idx);
    ushort4 o; o.x = f2bf(v.x); o.y = f2bf(v.y); o.z = f2bf(v.z); o.w = f2bf(v.w);
    *(ushort4*)(dst + idx) = o;
}

__global__ void prep_bias(const float* __restrict__ bih, const float* __restrict__ bhh,
                          float* __restrict__ bias) {
    int i = blockIdx.x * 256 + threadIdx.x;
    bias[i] = bih[i] + bhh[i];
}

// sorted h0 (bf16) and c0 (f32)
__global__ void prep_state(const float* __restrict__ h0, const float* __restrict__ c0,
                           const int* __restrict__ perm,
                           u16* __restrict__ hbuf0, float* __restrict__ c0p) {
    int i = blockIdx.x * 256 + threadIdx.x;           // [0, B*H)
    int srow = i >> 10, col = i & 1023;
    int orig = perm[srow];
    hbuf0[i] = f2bf(h0[(size_t)orig * H_ + col]);
    c0p[i]   = c0[(size_t)orig * H_ + col];
}

__global__ void zero_flags(u32* __restrict__ f) {
    f[blockIdx.x * 256 + threadIdx.x] = 0;            // 8KB, only 2KB used
}

// ---------------- persistent LSTM ----------------
// 256 blocks x 512 threads, 1 block/CU. grp = bid>>7 owns sorted rows
// [grp*128, grp*128+128); cb = bid&127 owns h-cols [8cb, 8cb+8) (32 gate-cols).
// Wave w owns 16-row tile w: loads MFMA A-fragments DIRECTLY from global
// (no LDS staging), computes 16x32 gates, epilogue, h-store.
// Sync: per-producer BYTE flags at flags_u8[(grp*8+w)*128 + cb] = (t+1)&0xff
// (plain relaxed agent stores -> fully parallel producers). Consumer polls
// 128 flags with 32 lanes x u32 (128B/poll, 4x less than round-0's 512B).
// Step order: issue emb loads -> poll -> issue h loads -> emb MFMAs (h loads
// in flight) -> h MFMAs. All global loads are inline-asm so the manual vmcnt
// schedule is exact.

__global__ __launch_bounds__(512, 2) void lstm_persist(
    const u16* __restrict__ emb, const u16* __restrict__ wcat,
    const float* __restrict__ bias, const float* __restrict__ c0p,
    const int* __restrict__ sxi,
    u16* __restrict__ hbuf, float* __restrict__ hn, u32* __restrict__ flags)
{
    __shared__ __align__(16) u16 Wl[32 * 1544];       // 98,816 B  weights
    __shared__ __align__(16) float Gf_all[8][640];    // 20,480 B  epilogue scratch

    const int tid  = threadIdx.x;
    const int w    = tid >> 6;
    const int lane = tid & 63;
    const int lr   = lane & 15;
    const int lk   = lane >> 4;
    const int grp  = blockIdx.x >> 7;
    const int cb   = blockIdx.x & 127;
    const int erow = lane >> 2;
    const int e2   = (lane & 3) * 2;
    const int rowg = grp * 128 + w * 16 + erow;       // epilogue/store (4 lanes/row)
    const int rowf = grp * 128 + w * 16 + lr;         // fragment loads (1 lane/row)

    // ---- one-time: weights -> LDS (rows: [i x8 | f x8 | g x8 | o x8]) ----
    for (int i = tid; i < 32 * 192; i += 512) {
        int r = i / 192, kq = i - r * 192;
        int gcol = (r >> 3) * H_ + cb * 8 + (r & 7);
        *(u32x4*)&Wl[r * 1544 + kq * 8] =
            *(const u32x4*)(wcat + (size_t)gcol * KCAT + kq * 8);
    }
    __syncthreads();   // the ONLY block barrier

    const int tmax_w   = sxi[grp * 128 + w * 16];
    const int xi_lane  = sxi[rowg];
    float2 cc = *(const float2*)(c0p + (size_t)rowg * H_ + cb * 8 + e2);
    const float2 bI = *(const float2*)(bias + 0 * H_ + cb * 8 + e2);
    const float2 bF = *(const float2*)(bias + 1 * H_ + cb * 8 + e2);
    const float2 bG = *(const float2*)(bias + 2 * H_ + cb * 8 + e2);
    const float2 bO = *(const float2*)(bias + 3 * H_ + cb * 8 + e2);

    unsigned char* fbase = (unsigned char*)flags;     // byte flags
    const u32* fpoll = (const u32*)(fbase + (grp * 8 + w) * 128);

    floatx4 acc0, acc1;
    // A-frags va0 (k kk..kk+32) and va1 (kk+32..kk+64) straight into MFMA.
    auto MFMA4 = [&](u32x4 va0, u32x4 va1, int kk) {
        short8 a0 = as_s8(va0), a1 = as_s8(va1);
        short8 b00 = *(const short8*)&Wl[lr * 1544 + kk + lk * 8];
        short8 b01 = *(const short8*)&Wl[(16 + lr) * 1544 + kk + lk * 8];
        acc0 = __builtin_amdgcn_mfma_f32_16x16x32_bf16(a0, b00, acc0, 0, 0, 0);
        acc1 = __builtin_amdgcn_mfma_f32_16x16x32_bf16(a0, b01, acc1, 0, 0, 0);
        short8 b10 = *(const short8*)&Wl[lr * 1544 + kk + 32 + lk * 8];
        short8 b11 = *(const short8*)&Wl[(16 + lr) * 1544 + kk + 32 + lk * 8];
        acc0 = __builtin_amdgcn_mfma_f32_16x16x32_bf16(a1, b10, acc0, 0, 0, 0);
        acc1 = __builtin_amdgcn_mfma_f32_16x16x32_bf16(a1, b11, acc1, 0, 0, 0);
    };

    for (int t = 0; t <= tmax_w; ++t) {
        const u16* hread  = hbuf + (size_t)(t & 1) * (B_ * H_);
        u16*       hwrite = hbuf + (size_t)((t + 1) & 1) * (B_ * H_);
        acc0 = (floatx4){0.f, 0.f, 0.f, 0.f};
        acc1 = (floatx4){0.f, 0.f, 0.f, 0.f};

        // ---- issue all 16 emb loads (plain cached) ----
        const u16* ebase = emb + ((size_t)rowf * T_ + t) * E_ + lk * 8;
        u32x4 ev[8][2];
        #pragma unroll
        for (int c = 0; c < 8; ++c) {
            ev[c][0] = load_g(ebase, c * 128);
            ev[c][1] = load_g(ebase, c * 128 + 64);
        }

        // ---- wait for h_t: 128 byte-flags, 32 lanes x u32, window compare ----
        if (t > 0) {
            const u32 t8 = (u32)t & 0xffu;
            while (true) {
                bool ok = true;
                if (lane < 32) {
                    u32 v = __hip_atomic_load(fpoll + lane, __ATOMIC_RELAXED,
                                              __HIP_MEMORY_SCOPE_AGENT);
                    #pragma unroll
                    for (int b2 = 0; b2 < 4; ++b2) {
                        u32 f = (v >> (8 * b2)) & 0xffu;
                        ok = ok && (((f - t8) & 0xffu) < 0x80u);
                    }
                }
                if (__all(ok)) break;
                __builtin_amdgcn_s_sleep(1);
            }
        }

        // ---- issue first 16 h loads (coherent), then overlap emb MFMAs ----
        const u16* hbase = hread + (size_t)rowf * H_ + lk * 8;
        u32x4 hv[8][2];
        #pragma unroll
        for (int c = 0; c < 8; ++c) {
            hv[c][0] = load_sc(hbase, c * 128);
            hv[c][1] = load_sc(hbase, c * 128 + 64);
        }

        // ---- emb phase (k 1024..1535) while h loads are in flight ----
        #pragma unroll
        for (int c = 0; c < 8; ++c) {
            asm volatile("s_waitcnt vmcnt(%0)" :: "i"(30 - 2 * c) : "memory");
            MFMA4(ev[c][0], ev[c][1], 1024 + c * 64);
        }

        // ---- h phase (k 0..1023), rolling re-issue, 16 in flight ----
        #pragma unroll
        for (int c = 0; c < 16; ++c) {
            const int pend = (c < 8) ? 14 : (30 - 2 * c);
            asm volatile("s_waitcnt vmcnt(%0)" :: "i"(pend) : "memory");
            u32x4 va0 = hv[c & 7][0], va1 = hv[c & 7][1];
            if (c < 8) {
                hv[c][0] = load_sc(hbase, (c + 8) * 128);
                hv[c][1] = load_sc(hbase, (c + 8) * 128 + 64);
            }
            MFMA4(va0, va1, c * 64);
        }

        // ---- epilogue: wave-internal LDS transpose ----
        float* Gf = Gf_all[w];                        // [4 gates][16 rows][10]
        #pragma unroll
        for (int ct = 0; ct < 2; ++ct) {
            const floatx4 aa = ct ? acc1 : acc0;
            const int gate = ct * 2 + (lr >> 3);
            const int hc   = lr & 7;
            #pragma unroll
            for (int r = 0; r < 4; ++r)
                Gf[(gate * 16 + lk * 4 + r) * 10 + hc] = aa[r];
        }
        float2 g_i = *(float2*)&Gf[(0 * 16 + erow) * 10 + e2];
        float2 g_f = *(float2*)&Gf[(1 * 16 + erow) * 10 + e2];
        float2 g_g = *(float2*)&Gf[(2 * 16 + erow) * 10 + e2];
        float2 g_o = *(float2*)&Gf[(3 * 16 + erow) * 10 + e2];

        float i0 = sigf(g_i.x + bI.x), i1 = sigf(g_i.y + bI.y);
        float f0 = sigf(g_f.x + bF.x), f1 = sigf(g_f.y + bF.y);
        float q0 = tanh_f(g_g.x + bG.x), q1 = tanh_f(g_g.y + bG.y);
        float o0 = sigf(g_o.x + bO.x), o1 = sigf(g_o.y + bO.y);
        cc.x = f0 * cc.x + i0 * q0;
        cc.y = f1 * cc.y + i1 * q1;
        float h0f = o0 * tanh_f(cc.x);
        float h1f = o1 * tanh_f(cc.y);

        u32 packed = (u32)f2bf(h0f) | ((u32)f2bf(h1f) << 16);
        __hip_atomic_store((u32*)(hwrite + (size_t)rowg * H_ + cb * 8 + e2),
                           packed, __ATOMIC_RELAXED, __HIP_MEMORY_SCOPE_AGENT);
        if (xi_lane == t)
            *(float2*)(hn + (size_t)rowg * H_ + cb * 8 + e2) = make_float2(h0f, h1f);
        asm volatile("s_waitcnt vmcnt(0)" ::: "memory");
        if (lane == 0)
            __hip_atomic_store(fbase + (grp * 8 + w) * 128 + cb,
                               (unsigned char)((t + 1) & 0xff),
                               __ATOMIC_RELAXED, __HIP_MEMORY_SCOPE_AGENT);
    }
}

// ---------------- tail ----------------

__global__ void hn_convert(const float* __restrict__ hn, u16* __restrict__ hnbf) {
    int i = blockIdx.x * 256 + threadIdx.x;
    hnbf[i] = f2bf(hn[i]);
}

__global__ __launch_bounds__(256) void fc1_kernel(
    const u16* __restrict__ A, const u16* __restrict__ Bw,
    const float* __restrict__ bvec, float* __restrict__ z)
{
    __shared__ __align__(16) u16 Als[64 * 72];
    __shared__ __align__(16) u16 Bls[64 * 72];
    const int tid = threadIdx.x;
    const int rowbase = blockIdx.y * 64;
    const int colbase = blockIdx.x * 64;
    floatx4 acc[4] = {{0,0,0,0},{0,0,0,0},{0,0,0,0},{0,0,0,0}};
    const int w = tid >> 6, lane = tid & 63, lr = lane & 15, lk = lane >> 4;

    for (int s = 0; s < H_ / 64; ++s) {
        int k0 = s * 64;
        #pragma unroll
        for (int cc2 = 0; cc2 < 2; ++cc2) {
            int c = tid + cc2 * 256;
            int row = c >> 3, kg = c & 7, kglob = k0 + kg * 8;
            *(u32x4*)&Als[(row * 9 + kg) * 8] =
                *(const u32x4*)(A + (size_t)(rowbase + row) * H_ + kglob);
            *(u32x4*)&Bls[(row * 9 + kg) * 8] =
                *(const u32x4*)(Bw + (size_t)(colbase + row) * H_ + kglob);
        }
        __syncthreads();
        #pragma unroll
        for (int ks = 0; ks < 2; ++ks) {
            short8 a = *(const short8*)&Als[((16 * w + lr) * 9 + ks * 4 + lk) * 8];
            #pragma unroll
            for (int q = 0; q < 4; ++q) {
                short8 b = *(const short8*)&Bls[((q * 16 + lr) * 9 + ks * 4 + lk) * 8];
                acc[q] = __builtin_amdgcn_mfma_f32_16x16x32_bf16(a, b, acc[q], 0, 0, 0);
            }
        }
        __syncthreads();
    }
    #pragma unroll
    for (int q = 0; q < 4; ++q) {
        int col = colbase + q * 16 + lr;
        float bb = bvec[col];
        #pragma unroll
        for (int r = 0; r < 4; ++r) {
            int row = rowbase + 16 * w + lk * 4 + r;
            z[(size_t)row * M_ + col] = tanh_f(acc[q][r] + bb);
        }
    }
}

__global__ __launch_bounds__(64) void fc2_softmax(
    const float* __restrict__ z, const float* __restrict__ wmat,
    const float* __restrict__ bvec, const int* __restrict__ perm,
    float* __restrict__ out)
{
    int bi = blockIdx.x;
    int lane = threadIdx.x;
    const float4* zr = (const float4*)(z + (size_t)bi * M_);
    const float4* w0 = (const float4*)(wmat);
    const float4* w1 = (const float4*)(wmat + M_);
    float s0 = 0.f, s1 = 0.f;
    for (int k = lane; k < M_ / 4; k += 64) {
        float4 zv = zr[k]; float4 a = w0[k]; float4 c = w1[k];
        s0 += zv.x * a.x + zv.y * a.y + zv.z * a.z + zv.w * a.w;
        s1 += zv.x * c.x + zv.y * c.y + zv.z * c.z + zv.w * c.w;
    }
    for (int off = 32; off; off >>= 1) {
        s0 += __shfl_down(s0, off);
        s1 += __shfl_down(s1, off);
    }
    if (lane == 0) {
        float l0 = s0 + bvec[0], l1 = s1 + bvec[1];
        float m = fmaxf(l0, l1);
        float lse = m + __logf(__expf(l0 - m) + __expf(l1 - m));
        int orig = perm[bi];
        out[orig * 2 + 0] = l0 - lse;
        out[orig * 2 + 1] = l1 - lse;
    }
}

// ---------------- launch ----------------

extern "C" void kernel_launch(void* const* d_in, const int* in_sizes, int n_in,
                              void* d_out, int out_size, void* d_ws, size_t ws_size,
                              hipStream_t stream)
{
    const int*   x       = (const int*)  d_in[0];
    const int*   x_index = (const int*)  d_in[1];
    const float* emb_t   = (const float*)d_in[2];
    const float* W_ih    = (const float*)d_in[3];
    const float* W_hh    = (const float*)d_in[4];
    const float* b_ih    = (const float*)d_in[5];
    const float* b_hh    = (const float*)d_in[6];
    const float* fc1_w   = (const float*)d_in[7];
    const float* fc1_b   = (const float*)d_in[8];
    const float* fc2_w   = (const float*)d_in[9];
    const float* fc2_b   = (const float*)d_in[10];
    const float* h0      = (const float*)d_in[11];
    const float* c0      = (const float*)d_in[12];
    float* out = (float*)d_out;

    char* p = (char*)d_ws;
    u16*   emb_bf = (u16*)p;   p += (size_t)B_ * T_ * E_ * 2;   // 134 MB
    u16*   wcat   = (u16*)p;   p += (size_t)G4H * KCAT * 2;     // 12.6 MB
    u16*   fc1wbf = (u16*)p;   p += (size_t)M_ * H_ * 2;        // 2 MB
    float* bias   = (float*)p; p += (size_t)G4H * 4;
    u16*   hbuf   = (u16*)p;   p += (size_t)2 * B_ * H_ * 2;    // ping-pong h
    float* c0p    = (float*)p; p += (size_t)B_ * H_ * 4;
    float* hn     = (float*)p; p += (size_t)B_ * H_ * 4;
    u16*   hnbf   = (u16*)p;   p += (size_t)B_ * H_ * 2;
    float* zbuf   = (float*)p; p += (size_t)B_ * M_ * 4;
    int*   perm   = (int*)p;   p += (size_t)B_ * 4;
    int*   sxi    = (int*)p;   p += (size_t)B_ * 4;
    u32*   flags  = (u32*)p;   p += (size_t)16 * 128 * 4;

    sort_rows <<<1,     256, 0, stream>>>(x_index, perm, sxi);
    prep_emb  <<<65536, 256, 0, stream>>>(x, emb_t, perm, emb_bf);
    prep_wcat <<<6144,  256, 0, stream>>>(W_hh, W_ih, wcat);
    prep_fc1w <<<1024,  256, 0, stream>>>(fc1_w, fc1wbf);
    prep_bias <<<16,    256, 0, stream>>>(b_ih, b_hh, bias);
    prep_state<<<1024,  256, 0, stream>>>(h0, c0, perm, hbuf, c0p);
    zero_flags<<<8,     256, 0, stream>>>(flags);

    lstm_persist<<<256, 512, 0, stream>>>(emb_bf, wcat, bias, c0p, sxi,
                                          hbuf, hn, flags);

    hn_convert <<<1024, 256, 0, stream>>>(hn, hnbf);
    fc1_kernel <<<dim3(16, 4), 256, 0, stream>>>(hnbf, fc1wbf, fc1_b, zbuf);
    fc2_softmax<<<256, 64, 0, stream>>>(zbuf, fc2_w, fc2_b, perm, out);
}

// Round 3
// 6408.832 us; speedup vs baseline: 1.6225x; 1.6225x over previous
//
#include <hip/hip_runtime.h>

typedef unsigned short u16;
typedef unsigned int u32;
typedef unsigned long long u64;
typedef __attribute__((ext_vector_type(8))) short short8;
typedef __attribute__((ext_vector_type(4))) float floatx4;
typedef __attribute__((ext_vector_type(4))) u32 u32x4;

#define B_   256
#define T_   512
#define E_   512
#define H_   1024
#define G4H  4096
#define KCAT 1536
#define M_   1024

__device__ __forceinline__ u16 f2bf(float f) {
    union { float f; unsigned u; } v; v.f = f;
    unsigned r = (v.u + 0x7fffu + ((v.u >> 16) & 1u)) >> 16;
    return (u16)r;
}
__device__ __forceinline__ float sigf(float x) {
    return __fdividef(1.0f, 1.0f + __expf(-x));
}
__device__ __forceinline__ float tanh_f(float x) {
    return 1.0f - __fdividef(2.0f, __expf(2.0f * x) + 1.0f);
}
// L2-scope load: sc0 bypasses L1, served by (and allocated in) this XCD's L2.
// Freshness vs other XCDs is provided manually via buffer_inv sc1 after the
// flag poll (producers store h with sc0 sc1 -> data is at MALL).
__device__ __forceinline__ u32x4 load_l2(const u16* p) {
    u32x4 r;
    asm volatile("global_load_dwordx4 %0, %1, off sc0"
                 : "=v"(r) : "v"(p) : "memory");
    return r;
}

// ---------------- prep kernels ----------------

// rank rows by x_index descending (stable): perm[rank]=orig, sxi[rank]=xi
__global__ void sort_rows(const int* __restrict__ x_index,
                          int* __restrict__ perm, int* __restrict__ sxi) {
    __shared__ int xl[B_];
    int tid = threadIdx.x;
    xl[tid] = x_index[tid];
    __syncthreads();
    int mine = xl[tid], rank = 0;
    for (int j = 0; j < B_; ++j)
        rank += (xl[j] > mine) || (xl[j] == mine && j < tid);
    perm[rank] = tid;
    sxi[rank] = mine;
}

// emb_bf[srow][t][e] = bf16(tab[x[perm[srow]][t]][e])
__global__ void prep_emb(const int* __restrict__ x, const float* __restrict__ tab,
                         const int* __restrict__ perm, u16* __restrict__ emb) {
    int idx = (blockIdx.x * 256 + threadIdx.x) * 4;   // [0, B*T*E)
    int srow = idx >> 18;                             // / (T*E)
    int t    = (idx >> 9) & 511;
    int e    = idx & 511;
    int orig = perm[srow];
    int xv   = x[orig * T_ + t];
    float4 v = *(const float4*)(tab + (size_t)xv * E_ + e);
    ushort4 o; o.x = f2bf(v.x); o.y = f2bf(v.y); o.z = f2bf(v.z); o.w = f2bf(v.w);
    *(ushort4*)(emb + idx) = o;
}

__global__ void prep_wcat(const float* __restrict__ Whh, const float* __restrict__ Wih,
                          u16* __restrict__ wcat) {
    int idx = (blockIdx.x * 256 + threadIdx.x) * 4;   // [0, 4096*1536)
    int g = idx / KCAT;
    int k = idx - g * KCAT;
    const float* src = (k < H_) ? (Whh + (size_t)g * H_ + k)
                                : (Wih + (size_t)g * E_ + (k - H_));
    float4 v = *(const float4*)src;
    ushort4 o; o.x = f2bf(v.x); o.y = f2bf(v.y); o.z = f2bf(v.z); o.w = f2bf(v.w);
    *(ushort4*)(wcat + idx) = o;
}

__global__ void prep_fc1w(const float* __restrict__ src, u16* __restrict__ dst) {
    int idx = (blockIdx.x * 256 + threadIdx.x) * 4;
    float4 v = *(const float4*)(src + idx);
    ushort4 o; o.x = f2bf(v.x); o.y = f2bf(v.y); o.z = f2bf(v.z); o.w = f2bf(v.w);
    *(ushort4*)(dst + idx) = o;
}

__global__ void prep_bias(const float* __restrict__ bih, const float* __restrict__ bhh,
                          float* __restrict__ bias) {
    int i = blockIdx.x * 256 + threadIdx.x;
    bias[i] = bih[i] + bhh[i];
}

// sorted h0 (bf16) and c0 (f32)
__global__ void prep_state(const float* __restrict__ h0, const float* __restrict__ c0,
                           const int* __restrict__ perm,
                           u16* __restrict__ hbuf0, float* __restrict__ c0p) {
    int i = blockIdx.x * 256 + threadIdx.x;           // [0, B*H)
    int srow = i >> 10, col = i & 1023;
    int orig = perm[srow];
    hbuf0[i] = f2bf(h0[(size_t)orig * H_ + col]);
    c0p[i]   = c0[(size_t)orig * H_ + col];
}

__global__ void zero_flags(u32* __restrict__ f) {
    f[blockIdx.x * 256 + threadIdx.x] = 0;            // [0, 16*128)
}

// ---------------- persistent LSTM ----------------
// 256 blocks x 512 threads, 1 block/CU. grp = bid>>7 owns sorted rows
// [grp*128, grp*128+128); cb = bid&127 owns h-cols [8cb, 8cb+8) (32 gate-cols).
// Wave w owns 16-row tile w: stages A, computes 16x32 gates, epilogue, h-store.
// NO __syncthreads in the step loop; cross-block sync = per-(grp,tile,cb)
// monotonic version flags at agent scope (u32, parallel plain stores).
// h visibility: producers store h sc0 sc1 (write-through to MALL). Consumers,
// AFTER the poll passes, invalidate their XCD's L2 (buffer_inv sc1 -- the
// agent-acquire-fence op; clean lines only) and read h with sc0 ONLY, so the
// 32 blocks of an XCD share one L2 fill of the 512KB/step h working set
// instead of 32 redundant MALL reads (was 64 MB/step of sc0 sc1 traffic).
// Nothing we need is ever dirty in L2 during this kernel (h, flags, hn all
// stored with sc0 sc1).

__global__ __launch_bounds__(512, 2) void lstm_persist(
    const u16* __restrict__ emb, const u16* __restrict__ wcat,
    const float* __restrict__ bias, const float* __restrict__ c0p,
    const int* __restrict__ sxi,
    u16* __restrict__ hbuf, float* __restrict__ hn, u32* __restrict__ flags)
{
    __shared__ __align__(16) u16 Wl[32 * 1544];       // 98,816 B  weights
    __shared__ __align__(16) u16 Al[8 * 2 * 1152];    // 36,864 B  per-wave A dbuf

    const int tid  = threadIdx.x;
    const int w    = tid >> 6;
    const int lane = tid & 63;
    const int lr   = lane & 15;
    const int lk   = lane >> 4;
    const int grp  = blockIdx.x >> 7;
    const int cb   = blockIdx.x & 127;
    const int erow = lane >> 2;
    const int e2   = (lane & 3) * 2;
    const int rowg = grp * 128 + w * 16 + erow;

    // ---- one-time: weights -> LDS (rows: [i x8 | f x8 | g x8 | o x8]) ----
    for (int i = tid; i < 32 * 192; i += 512) {
        int r = i / 192, kq = i - r * 192;
        int gcol = (r >> 3) * H_ + cb * 8 + (r & 7);
        *(u32x4*)&Wl[r * 1544 + kq * 8] =
            *(const u32x4*)(wcat + (size_t)gcol * KCAT + kq * 8);
    }
    __syncthreads();   // the ONLY block barrier

    const int tmax_w   = sxi[grp * 128 + w * 16];
    const int xi_lane  = sxi[rowg];
    float2 cc = *(const float2*)(c0p + (size_t)rowg * H_ + cb * 8 + e2);
    const float2 bI = *(const float2*)(bias + 0 * H_ + cb * 8 + e2);
    const float2 bF = *(const float2*)(bias + 1 * H_ + cb * 8 + e2);
    const float2 bG = *(const float2*)(bias + 2 * H_ + cb * 8 + e2);
    const float2 bO = *(const float2*)(bias + 3 * H_ + cb * 8 + e2);

    floatx4 acc0, acc1;
    auto MFMA_CHUNK = [&](int sbase, int kk) {
        #pragma unroll
        for (int ks = 0; ks < 2; ++ks) {
            short8 a  = *(const short8*)&Al[sbase + lr * 72 + (ks * 4 + lk) * 8];
            short8 b0 = *(const short8*)&Wl[lr * 1544 + kk + ks * 32 + lk * 8];
            short8 b1 = *(const short8*)&Wl[(16 + lr) * 1544 + kk + ks * 32 + lk * 8];
            acc0 = __builtin_amdgcn_mfma_f32_16x16x32_bf16(a, b0, acc0, 0, 0, 0);
            acc1 = __builtin_amdgcn_mfma_f32_16x16x32_bf16(a, b1, acc1, 0, 0, 0);
        }
    };
    auto STAGE_WRITE = [&](int slot, u32x4 v0, u32x4 v1) {
        int el = (w * 2 + slot) * 1152 + erow * 72 + (lane & 3) * 16;
        *(u32x4*)&Al[el]     = v0;
        *(u32x4*)&Al[el + 8] = v1;
    };

    for (int t = 0; t <= tmax_w; ++t) {
        const u16* hread  = hbuf + (size_t)(t & 1) * (B_ * H_);
        u16*       hwrite = hbuf + (size_t)((t + 1) & 1) * (B_ * H_);
        acc0 = (floatx4){0.f, 0.f, 0.f, 0.f};
        acc1 = (floatx4){0.f, 0.f, 0.f, 0.f};

        // ---- emb phase (k 1024..1535), plain cached loads, depth-4 ----
        {
            const u16* ebase = emb + ((size_t)rowg * T_ + t) * E_ + (lane & 3) * 16;
            u32x4 ev[4][2];
            #pragma unroll
            for (int c = 0; c < 4; ++c) {
                ev[c][0] = *(const u32x4*)(ebase + c * 64);
                ev[c][1] = *(const u32x4*)(ebase + c * 64 + 8);
            }
            #pragma unroll
            for (int ce = 0; ce < 8; ++ce) {
                STAGE_WRITE(ce & 1, ev[ce & 3][0], ev[ce & 3][1]);
                if (ce < 4) {
                    ev[ce & 3][0] = *(const u32x4*)(ebase + (ce + 4) * 64);
                    ev[ce & 3][1] = *(const u32x4*)(ebase + (ce + 4) * 64 + 8);
                }
                MFMA_CHUNK((w * 2 + (ce & 1)) * 1152, 1024 + ce * 64);
            }
        }

        // ---- wait for h_t (tile w of all 128 blocks in our group) ----
        if (t > 0) {
            u64* fp = (u64*)(flags + (grp * 8 + w) * 128);
            while (true) {
                u64 v = __hip_atomic_load(&fp[lane], __ATOMIC_RELAXED,
                                          __HIP_MEMORY_SCOPE_AGENT);
                if (__all(((u32)v >= (u32)t) && ((u32)(v >> 32) >= (u32)t))) break;
                __builtin_amdgcn_s_sleep(1);
            }
            // acquire: drop (clean) stale lines in this XCD's L2 so the sc0
            // h loads below observe the producers' MALL data via L2.
            asm volatile("buffer_inv sc1" ::: "memory");
        }

        // ---- h phase (k 0..1023), L2-scope loads, 8-chunk pipeline ----
        {
            const u16* hbase = hread + (size_t)rowg * H_ + (lane & 3) * 16;
            u32x4 hv[8][2];
            #pragma unroll
            for (int c = 0; c < 8; ++c) {
                hv[c][0] = load_l2(hbase + c * 64);
                hv[c][1] = load_l2(hbase + c * 64 + 8);
            }
            #pragma unroll
            for (int c = 0; c < 16; ++c) {
                const int pend = (c < 8) ? 14 : (30 - 2 * c);
                asm volatile("s_waitcnt vmcnt(%0)" :: "i"(pend) : "memory");
                STAGE_WRITE(c & 1, hv[c & 7][0], hv[c & 7][1]);
                if (c < 8) {
                    hv[c][0] = load_l2(hbase + (c + 8) * 64);
                    hv[c][1] = load_l2(hbase + (c + 8) * 64 + 8);
                }
                MFMA_CHUNK((w * 2 + (c & 1)) * 1152, c * 64);
            }
        }

        // ---- epilogue: wave-internal LDS transpose (reuse A region) ----
        float* Gf = (float*)&Al[(w * 2) * 1152];      // [4 gates][16 rows][10]
        #pragma unroll
        for (int ct = 0; ct < 2; ++ct) {
            const floatx4 aa = ct ? acc1 : acc0;
            const int gate = ct * 2 + (lr >> 3);
            const int hc   = lr & 7;
            #pragma unroll
            for (int r = 0; r < 4; ++r)
                Gf[(gate * 16 + lk * 4 + r) * 10 + hc] = aa[r];
        }
        float2 g_i = *(float2*)&Gf[(0 * 16 + erow) * 10 + e2];
        float2 g_f = *(float2*)&Gf[(1 * 16 + erow) * 10 + e2];
        float2 g_g = *(float2*)&Gf[(2 * 16 + erow) * 10 + e2];
        float2 g_o = *(float2*)&Gf[(3 * 16 + erow) * 10 + e2];

        float i0 = sigf(g_i.x + bI.x), i1 = sigf(g_i.y + bI.y);
        float f0 = sigf(g_f.x + bF.x), f1 = sigf(g_f.y + bF.y);
        float q0 = tanh_f(g_g.x + bG.x), q1 = tanh_f(g_g.y + bG.y);
        float o0 = sigf(g_o.x + bO.x), o1 = sigf(g_o.y + bO.y);
        cc.x = f0 * cc.x + i0 * q0;
        cc.y = f1 * cc.y + i1 * q1;
        float h0f = o0 * tanh_f(cc.x);
        float h1f = o1 * tanh_f(cc.y);

        u32 packed = (u32)f2bf(h0f) | ((u32)f2bf(h1f) << 16);
        __hip_atomic_store((u32*)(hwrite + (size_t)rowg * H_ + cb * 8 + e2),
                           packed, __ATOMIC_RELAXED, __HIP_MEMORY_SCOPE_AGENT);
        if (xi_lane == t) {
            float2 hv2 = make_float2(h0f, h1f);
            // sc0 sc1 store: keep hn out of L2 so buffer_inv can't interact
            asm volatile("global_store_dwordx2 %0, %1, off sc0 sc1"
                         :: "v"(hn + (size_t)rowg * H_ + cb * 8 + e2), "v"(hv2)
                         : "memory");
        }
        asm volatile("s_waitcnt vmcnt(0)" ::: "memory");
        if (lane == 0)
            __hip_atomic_store(flags + (grp * 8 + w) * 128 + cb, (u32)(t + 1),
                               __ATOMIC_RELAXED, __HIP_MEMORY_SCOPE_AGENT);
    }
}

// ---------------- tail ----------------

__global__ void hn_convert(const float* __restrict__ hn, u16* __restrict__ hnbf) {
    int i = blockIdx.x * 256 + threadIdx.x;
    hnbf[i] = f2bf(hn[i]);
}

__global__ __launch_bounds__(256) void fc1_kernel(
    const u16* __restrict__ A, const u16* __restrict__ Bw,
    const float* __restrict__ bvec, float* __restrict__ z)
{
    __shared__ __align__(16) u16 Als[64 * 72];
    __shared__ __align__(16) u16 Bls[64 * 72];
    const int tid = threadIdx.x;
    const int rowbase = blockIdx.y * 64;
    const int colbase = blockIdx.x * 64;
    floatx4 acc[4] = {{0,0,0,0},{0,0,0,0},{0,0,0,0},{0,0,0,0}};
    const int w = tid >> 6, lane = tid & 63, lr = lane & 15, lk = lane >> 4;

    for (int s = 0; s < H_ / 64; ++s) {
        int k0 = s * 64;
        #pragma unroll
        for (int cc2 = 0; cc2 < 2; ++cc2) {
            int c = tid + cc2 * 256;
            int row = c >> 3, kg = c & 7, kglob = k0 + kg * 8;
            *(u32x4*)&Als[(row * 9 + kg) * 8] =
                *(const u32x4*)(A + (size_t)(rowbase + row) * H_ + kglob);
            *(u32x4*)&Bls[(row * 9 + kg) * 8] =
                *(const u32x4*)(Bw + (size_t)(colbase + row) * H_ + kglob);
        }
        __syncthreads();
        #pragma unroll
        for (int ks = 0; ks < 2; ++ks) {
            short8 a = *(const short8*)&Als[((16 * w + lr) * 9 + ks * 4 + lk) * 8];
            #pragma unroll
            for (int q = 0; q < 4; ++q) {
                short8 b = *(const short8*)&Bls[((q * 16 + lr) * 9 + ks * 4 + lk) * 8];
                acc[q] = __builtin_amdgcn_mfma_f32_16x16x32_bf16(a, b, acc[q], 0, 0, 0);
            }
        }
        __syncthreads();
    }
    #pragma unroll
    for (int q = 0; q < 4; ++q) {
        int col = colbase + q * 16 + lr;
        float bb = bvec[col];
        #pragma unroll
        for (int r = 0; r < 4; ++r) {
            int row = rowbase + 16 * w + lk * 4 + r;
            z[(size_t)row * M_ + col] = tanh_f(acc[q][r] + bb);
        }
    }
}

__global__ __launch_bounds__(64) void fc2_softmax(
    const float* __restrict__ z, const float* __restrict__ wmat,
    const float* __restrict__ bvec, const int* __restrict__ perm,
    float* __restrict__ out)
{
    int bi = blockIdx.x;
    int lane = threadIdx.x;
    const float4* zr = (const float4*)(z + (size_t)bi * M_);
    const float4* w0 = (const float4*)(wmat);
    const float4* w1 = (const float4*)(wmat + M_);
    float s0 = 0.f, s1 = 0.f;
    for (int k = lane; k < M_ / 4; k += 64) {
        float4 zv = zr[k]; float4 a = w0[k]; float4 c = w1[k];
        s0 += zv.x * a.x + zv.y * a.y + zv.z * a.z + zv.w * a.w;
        s1 += zv.x * c.x + zv.y * c.y + zv.z * c.z + zv.w * c.w;
    }
    for (int off = 32; off; off >>= 1) {
        s0 += __shfl_down(s0, off);
        s1 += __shfl_down(s1, off);
    }
    if (lane == 0) {
        float l0 = s0 + bvec[0], l1 = s1 + bvec[1];
        float m = fmaxf(l0, l1);
        float lse = m + __logf(__expf(l0 - m) + __expf(l1 - m));
        int orig = perm[bi];
        out[orig * 2 + 0] = l0 - lse;
        out[orig * 2 + 1] = l1 - lse;
    }
}

// ---------------- launch ----------------

extern "C" void kernel_launch(void* const* d_in, const int* in_sizes, int n_in,
                              void* d_out, int out_size, void* d_ws, size_t ws_size,
                              hipStream_t stream)
{
    const int*   x       = (const int*)  d_in[0];
    const int*   x_index = (const int*)  d_in[1];
    const float* emb_t   = (const float*)d_in[2];
    const float* W_ih    = (const float*)d_in[3];
    const float* W_hh    = (const float*)d_in[4];
    const float* b_ih    = (const float*)d_in[5];
    const float* b_hh    = (const float*)d_in[6];
    const float* fc1_w   = (const float*)d_in[7];
    const float* fc1_b   = (const float*)d_in[8];
    const float* fc2_w   = (const float*)d_in[9];
    const float* fc2_b   = (const float*)d_in[10];
    const float* h0      = (const float*)d_in[11];
    const float* c0      = (const float*)d_in[12];
    float* out = (float*)d_out;

    char* p = (char*)d_ws;
    u16*   emb_bf = (u16*)p;   p += (size_t)B_ * T_ * E_ * 2;   // 134 MB
    u16*   wcat   = (u16*)p;   p += (size_t)G4H * KCAT * 2;     // 12.6 MB
    u16*   fc1wbf = (u16*)p;   p += (size_t)M_ * H_ * 2;        // 2 MB
    float* bias   = (float*)p; p += (size_t)G4H * 4;
    u16*   hbuf   = (u16*)p;   p += (size_t)2 * B_ * H_ * 2;    // ping-pong h
    float* c0p    = (float*)p; p += (size_t)B_ * H_ * 4;
    float* hn     = (float*)p; p += (size_t)B_ * H_ * 4;
    u16*   hnbf   = (u16*)p;   p += (size_t)B_ * H_ * 2;
    float* zbuf   = (float*)p; p += (size_t)B_ * M_ * 4;
    int*   perm   = (int*)p;   p += (size_t)B_ * 4;
    int*   sxi    = (int*)p;   p += (size_t)B_ * 4;
    u32*   flags  = (u32*)p;   p += (size_t)16 * 128 * 4;

    sort_rows <<<1,     256, 0, stream>>>(x_index, perm, sxi);
    prep_emb  <<<65536, 256, 0, stream>>>(x, emb_t, perm, emb_bf);
    prep_wcat <<<6144,  256, 0, stream>>>(W_hh, W_ih, wcat);
    prep_fc1w <<<1024,  256, 0, stream>>>(fc1_w, fc1wbf);
    prep_bias <<<16,    256, 0, stream>>>(b_ih, b_hh, bias);
    prep_state<<<1024,  256, 0, stream>>>(h0, c0, perm, hbuf, c0p);
    zero_flags<<<8,     256, 0, stream>>>(flags);

    lstm_persist<<<256, 512, 0, stream>>>(emb_bf, wcat, bias, c0p, sxi,
                                          hbuf, hn, flags);

    hn_convert <<<1024, 256, 0, stream>>>(hn, hnbf);
    fc1_kernel <<<dim3(16, 4), 256, 0, stream>>>(hnbf, fc1wbf, fc1_b, zbuf);
    fc2_softmax<<<256, 64, 0, stream>>>(zbuf, fc2_w, fc2_b, perm, out);
}

// Round 7
// 5054.185 us; speedup vs baseline: 2.0573x; 1.2680x over previous
//
#include <hip/hip_runtime.h>

typedef unsigned short u16;
typedef unsigned int u32;
typedef unsigned long long u64;
typedef __attribute__((ext_vector_type(8))) short short8;
typedef __attribute__((ext_vector_type(4))) float floatx4;
typedef __attribute__((ext_vector_type(4))) u32 u32x4;

#define B_   256
#define T_   512
#define E_   512
#define H_   1024
#define G4H  4096
#define KCAT 1536
#define M_   1024

__device__ __forceinline__ u16 f2bf(float f) {
    union { float f; unsigned u; } v; v.f = f;
    unsigned r = (v.u + 0x7fffu + ((v.u >> 16) & 1u)) >> 16;
    return (u16)r;
}
__device__ __forceinline__ float sigf(float x) {
    return __fdividef(1.0f, 1.0f + __expf(-x));
}
__device__ __forceinline__ float tanh_f(float x) {
    return 1.0f - __fdividef(2.0f, __expf(2.0f * x) + 1.0f);
}
// device-coherent 16B load (bypass L1/L2 -> always fresh at MALL), BYTE imm
__device__ __forceinline__ u32x4 load_sc(const u16* p, int imm) {
    u32x4 r;
    asm volatile("global_load_dwordx4 %0, %1, off offset:%2 sc0 sc1"
                 : "=v"(r) : "v"(p), "i"(imm) : "memory");
    return r;
}
__device__ __forceinline__ short8 as_s8(u32x4 v) {
    union { u32x4 u; short8 s; } x; x.u = v; return x.s;
}

// ---------------- prep kernels ----------------

// rank rows by x_index descending (stable): perm[rank]=orig, sxi[rank]=xi
__global__ void sort_rows(const int* __restrict__ x_index,
                          int* __restrict__ perm, int* __restrict__ sxi) {
    __shared__ int xl[B_];
    int tid = threadIdx.x;
    xl[tid] = x_index[tid];
    __syncthreads();
    int mine = xl[tid], rank = 0;
    for (int j = 0; j < B_; ++j)
        rank += (xl[j] > mine) || (xl[j] == mine && j < tid);
    perm[rank] = tid;
    sxi[rank] = mine;
}

// emb_bf[srow][t][e] = bf16(tab[x[perm[srow]][t]][e])
__global__ void prep_emb(const int* __restrict__ x, const float* __restrict__ tab,
                         const int* __restrict__ perm, u16* __restrict__ emb) {
    int idx = (blockIdx.x * 256 + threadIdx.x) * 4;   // [0, B*T*E)
    int srow = idx >> 18;                             // / (T*E)
    int t    = (idx >> 9) & 511;
    int e    = idx & 511;
    int orig = perm[srow];
    int xv   = x[orig * T_ + t];
    float4 v = *(const float4*)(tab + (size_t)xv * E_ + e);
    ushort4 o; o.x = f2bf(v.x); o.y = f2bf(v.y); o.z = f2bf(v.z); o.w = f2bf(v.w);
    *(ushort4*)(emb + idx) = o;
}

__global__ void prep_wcat(const float* __restrict__ Whh, const float* __restrict__ Wih,
                          u16* __restrict__ wcat) {
    int idx = (blockIdx.x * 256 + threadIdx.x) * 4;   // [0, 4096*1536)
    int g = idx / KCAT;
    int k = idx - g * KCAT;
    const float* src = (k < H_) ? (Whh + (size_t)g * H_ + k)
                                : (Wih + (size_t)g * E_ + (k - H_));
    float4 v = *(const float4*)src;
    ushort4 o; o.x = f2bf(v.x); o.y = f2bf(v.y); o.z = f2bf(v.z); o.w = f2bf(v.w);
    *(ushort4*)(wcat + idx) = o;
}

__global__ void prep_fc1w(const float* __restrict__ src, u16* __restrict__ dst) {
    int idx = (blockIdx.x * 256 + threadIdx.x) * 4;
    float4 v = *(const float4*)(src + idx);
    ushort4 o; o.x = f2bf(v.x); o.y = f2bf(v.y); o.z = f2bf(v.z); o.w = f2bf(v.w);
    *(ushort4*)(dst + idx) = o;
}

__global__ void prep_bias(const float* __restrict__ bih, const float* __restrict__ bhh,
                          float* __restrict__ bias) {
    int i = blockIdx.x * 256 + threadIdx.x;
    bias[i] = bih[i] + bhh[i];
}

// sorted h0 (bf16) and c0 (f32)
__global__ void prep_state(const float* __restrict__ h0, const float* __restrict__ c0,
                           const int* __restrict__ perm,
                           u16* __restrict__ hbuf0, float* __restrict__ c0p) {
    int i = blockIdx.x * 256 + threadIdx.x;           // [0, B*H)
    int srow = i >> 10, col = i & 1023;
    int orig = perm[srow];
    hbuf0[i] = f2bf(h0[(size_t)orig * H_ + col]);
    c0p[i]   = c0[(size_t)orig * H_ + col];
}

__global__ void zero_flags(u32* __restrict__ f) {
    f[blockIdx.x * 256 + threadIdx.x] = 0;            // [0, 16*128)
}

// ---------------- persistent LSTM ----------------
// 256 blocks x 512 threads, 1 block/CU. grp = bid>>7 owns sorted rows
// [grp*128, grp*128+128); cb = bid&127 owns h-cols [8cb, 8cb+8) (32 gate-cols).
// Wave w owns 16-row tile w: loads MFMA A-fragments DIRECTLY from global
// (no LDS staging — round-1-verified), computes 16x32 gates, epilogue, h-store.
// Sync = round-0-verified protocol: per-(grp,tile,cb) monotonic u32 flags,
// parallel per-wave lane-0 stores, 64-lane u64 poll. No __syncthreads in the
// step loop. Step order: emb phase fully (plain compiler-tracked loads, all
// consumed -> vmcnt==0 at poll) -> poll -> h phase (asm sc0sc1 loads with
// exact manual vmcnt pipeline, round-1-verified constants).

__global__ __launch_bounds__(512, 2) void lstm_persist(
    const u16* __restrict__ emb, const u16* __restrict__ wcat,
    const float* __restrict__ bias, const float* __restrict__ c0p,
    const int* __restrict__ sxi,
    u16* __restrict__ hbuf, float* __restrict__ hn, u32* __restrict__ flags)
{
    __shared__ __align__(16) u16 Wl[32 * 1544];       // 98,816 B  weights
    __shared__ __align__(16) float Gf_all[8][640];    // 20,480 B  epilogue scratch

    const int tid  = threadIdx.x;
    const int w    = tid >> 6;
    const int lane = tid & 63;
    const int lr   = lane & 15;
    const int lk   = lane >> 4;
    const int grp  = blockIdx.x >> 7;
    const int cb   = blockIdx.x & 127;
    const int erow = lane >> 2;
    const int e2   = (lane & 3) * 2;
    const int rowg = grp * 128 + w * 16 + erow;       // epilogue/store (4 lanes/row)
    const int rowf = grp * 128 + w * 16 + lr;         // fragment loads (1 lane/row)

    // ---- one-time: weights -> LDS (rows: [i x8 | f x8 | g x8 | o x8]) ----
    for (int i = tid; i < 32 * 192; i += 512) {
        int r = i / 192, kq = i - r * 192;
        int gcol = (r >> 3) * H_ + cb * 8 + (r & 7);
        *(u32x4*)&Wl[r * 1544 + kq * 8] =
            *(const u32x4*)(wcat + (size_t)gcol * KCAT + kq * 8);
    }
    __syncthreads();   // the ONLY block barrier

    const int tmax_w   = sxi[grp * 128 + w * 16];
    const int xi_lane  = sxi[rowg];
    float2 cc = *(const float2*)(c0p + (size_t)rowg * H_ + cb * 8 + e2);
    const float2 bI = *(const float2*)(bias + 0 * H_ + cb * 8 + e2);
    const float2 bF = *(const float2*)(bias + 1 * H_ + cb * 8 + e2);
    const float2 bG = *(const float2*)(bias + 2 * H_ + cb * 8 + e2);
    const float2 bO = *(const float2*)(bias + 3 * H_ + cb * 8 + e2);

    floatx4 acc0, acc1;
    // A-frags va0 (k kk..kk+32) and va1 (kk+32..kk+64) straight into MFMA.
    auto MFMA4 = [&](u32x4 va0, u32x4 va1, int kk) {
        short8 a0 = as_s8(va0), a1 = as_s8(va1);
        short8 b00 = *(const short8*)&Wl[lr * 1544 + kk + lk * 8];
        short8 b01 = *(const short8*)&Wl[(16 + lr) * 1544 + kk + lk * 8];
        acc0 = __builtin_amdgcn_mfma_f32_16x16x32_bf16(a0, b00, acc0, 0, 0, 0);
        acc1 = __builtin_amdgcn_mfma_f32_16x16x32_bf16(a0, b01, acc1, 0, 0, 0);
        short8 b10 = *(const short8*)&Wl[lr * 1544 + kk + 32 + lk * 8];
        short8 b11 = *(const short8*)&Wl[(16 + lr) * 1544 + kk + 32 + lk * 8];
        acc0 = __builtin_amdgcn_mfma_f32_16x16x32_bf16(a1, b10, acc0, 0, 0, 0);
        acc1 = __builtin_amdgcn_mfma_f32_16x16x32_bf16(a1, b11, acc1, 0, 0, 0);
    };

    for (int t = 0; t <= tmax_w; ++t) {
        const u16* hread  = hbuf + (size_t)(t & 1) * (B_ * H_);
        u16*       hwrite = hbuf + (size_t)((t + 1) & 1) * (B_ * H_);
        acc0 = (floatx4){0.f, 0.f, 0.f, 0.f};
        acc1 = (floatx4){0.f, 0.f, 0.f, 0.f};

        // ---- emb phase (k 1024..1535): plain cached loads, fully consumed
        //      before the poll so vmcnt==0 when the h pipeline starts ----
        {
            const u16* ebase = emb + ((size_t)rowf * T_ + t) * E_ + lk * 8;
            u32x4 ev[8][2];
            #pragma unroll
            for (int c = 0; c < 8; ++c) {
                ev[c][0] = *(const u32x4*)(ebase + c * 64);
                ev[c][1] = *(const u32x4*)(ebase + c * 64 + 32);
            }
            #pragma unroll
            for (int c = 0; c < 8; ++c)
                MFMA4(ev[c][0], ev[c][1], 1024 + c * 64);
        }

        // ---- wait for h_t (tile w of all 128 blocks in our group) ----
        if (t > 0) {
            u64* fp = (u64*)(flags + (grp * 8 + w) * 128);
            while (true) {
                u64 v = __hip_atomic_load(&fp[lane], __ATOMIC_RELAXED,
                                          __HIP_MEMORY_SCOPE_AGENT);
                if (__all(((u32)v >= (u32)t) && ((u32)(v >> 32) >= (u32)t))) break;
                __builtin_amdgcn_s_sleep(1);
            }
        }

        // ---- h phase (k 0..1023), coherent asm loads, rolling 16-deep ----
        {
            const u16* hbase = hread + (size_t)rowf * H_ + lk * 8;
            u32x4 hv[8][2];
            #pragma unroll
            for (int c = 0; c < 8; ++c) {
                hv[c][0] = load_sc(hbase, c * 128);
                hv[c][1] = load_sc(hbase, c * 128 + 64);
            }
            #pragma unroll
            for (int c = 0; c < 16; ++c) {
                const int pend = (c < 8) ? 14 : (30 - 2 * c);
                asm volatile("s_waitcnt vmcnt(%0)" :: "i"(pend) : "memory");
                u32x4 va0 = hv[c & 7][0], va1 = hv[c & 7][1];
                if (c < 8) {
                    hv[c][0] = load_sc(hbase, (c + 8) * 128);
                    hv[c][1] = load_sc(hbase, (c + 8) * 128 + 64);
                }
                MFMA4(va0, va1, c * 64);
            }
        }

        // ---- epilogue: wave-internal LDS transpose ----
        float* Gf = Gf_all[w];                        // [4 gates][16 rows][10]
        #pragma unroll
        for (int ct = 0; ct < 2; ++ct) {
            const floatx4 aa = ct ? acc1 : acc0;
            const int gate = ct * 2 + (lr >> 3);
            const int hc   = lr & 7;
            #pragma unroll
            for (int r = 0; r < 4; ++r)
                Gf[(gate * 16 + lk * 4 + r) * 10 + hc] = aa[r];
        }
        float2 g_i = *(float2*)&Gf[(0 * 16 + erow) * 10 + e2];
        float2 g_f = *(float2*)&Gf[(1 * 16 + erow) * 10 + e2];
        float2 g_g = *(float2*)&Gf[(2 * 16 + erow) * 10 + e2];
        float2 g_o = *(float2*)&Gf[(3 * 16 + erow) * 10 + e2];

        float i0 = sigf(g_i.x + bI.x), i1 = sigf(g_i.y + bI.y);
        float f0 = sigf(g_f.x + bF.x), f1 = sigf(g_f.y + bF.y);
        float q0 = tanh_f(g_g.x + bG.x), q1 = tanh_f(g_g.y + bG.y);
        float o0 = sigf(g_o.x + bO.x), o1 = sigf(g_o.y + bO.y);
        cc.x = f0 * cc.x + i0 * q0;
        cc.y = f1 * cc.y + i1 * q1;
        float h0f = o0 * tanh_f(cc.x);
        float h1f = o1 * tanh_f(cc.y);

        u32 packed = (u32)f2bf(h0f) | ((u32)f2bf(h1f) << 16);
        __hip_atomic_store((u32*)(hwrite + (size_t)rowg * H_ + cb * 8 + e2),
                           packed, __ATOMIC_RELAXED, __HIP_MEMORY_SCOPE_AGENT);
        if (xi_lane == t)
            *(float2*)(hn + (size_t)rowg * H_ + cb * 8 + e2) = make_float2(h0f, h1f);
        asm volatile("s_waitcnt vmcnt(0)" ::: "memory");
        if (lane == 0)
            __hip_atomic_store(flags + (grp * 8 + w) * 128 + cb, (u32)(t + 1),
                               __ATOMIC_RELAXED, __HIP_MEMORY_SCOPE_AGENT);
    }
}

// ---------------- tail ----------------

__global__ void hn_convert(const float* __restrict__ hn, u16* __restrict__ hnbf) {
    int i = blockIdx.x * 256 + threadIdx.x;
    hnbf[i] = f2bf(hn[i]);
}

__global__ __launch_bounds__(256) void fc1_kernel(
    const u16* __restrict__ A, const u16* __restrict__ Bw,
    const float* __restrict__ bvec, float* __restrict__ z)
{
    __shared__ __align__(16) u16 Als[64 * 72];
    __shared__ __align__(16) u16 Bls[64 * 72];
    const int tid = threadIdx.x;
    const int rowbase = blockIdx.y * 64;
    const int colbase = blockIdx.x * 64;
    floatx4 acc[4] = {{0,0,0,0},{0,0,0,0},{0,0,0,0},{0,0,0,0}};
    const int w = tid >> 6, lane = tid & 63, lr = lane & 15, lk = lane >> 4;

    for (int s = 0; s < H_ / 64; ++s) {
        int k0 = s * 64;
        #pragma unroll
        for (int cc2 = 0; cc2 < 2; ++cc2) {
            int c = tid + cc2 * 256;
            int row = c >> 3, kg = c & 7, kglob = k0 + kg * 8;
            *(u32x4*)&Als[(row * 9 + kg) * 8] =
                *(const u32x4*)(A + (size_t)(rowbase + row) * H_ + kglob);
            *(u32x4*)&Bls[(row * 9 + kg) * 8] =
                *(const u32x4*)(Bw + (size_t)(colbase + row) * H_ + kglob);
        }
        __syncthreads();
        #pragma unroll
        for (int ks = 0; ks < 2; ++ks) {
            short8 a = *(const short8*)&Als[((16 * w + lr) * 9 + ks * 4 + lk) * 8];
            #pragma unroll
            for (int q = 0; q < 4; ++q) {
                short8 b = *(const short8*)&Bls[((q * 16 + lr) * 9 + ks * 4 + lk) * 8];
                acc[q] = __builtin_amdgcn_mfma_f32_16x16x32_bf16(a, b, acc[q], 0, 0, 0);
            }
        }
        __syncthreads();
    }
    #pragma unroll
    for (int q = 0; q < 4; ++q) {
        int col = colbase + q * 16 + lr;
        float bb = bvec[col];
        #pragma unroll
        for (int r = 0; r < 4; ++r) {
            int row = rowbase + 16 * w + lk * 4 + r;
            z[(size_t)row * M_ + col] = tanh_f(acc[q][r] + bb);
        }
    }
}

__global__ __launch_bounds__(64) void fc2_softmax(
    const float* __restrict__ z, const float* __restrict__ wmat,
    const float* __restrict__ bvec, const int* __restrict__ perm,
    float* __restrict__ out)
{
    int bi = blockIdx.x;
    int lane = threadIdx.x;
    const float4* zr = (const float4*)(z + (size_t)bi * M_);
    const float4* w0 = (const float4*)(wmat);
    const float4* w1 = (const float4*)(wmat + M_);
    float s0 = 0.f, s1 = 0.f;
    for (int k = lane; k < M_ / 4; k += 64) {
        float4 zv = zr[k]; float4 a = w0[k]; float4 c = w1[k];
        s0 += zv.x * a.x + zv.y * a.y + zv.z * a.z + zv.w * a.w;
        s1 += zv.x * c.x + zv.y * c.y + zv.z * c.z + zv.w * c.w;
    }
    for (int off = 32; off; off >>= 1) {
        s0 += __shfl_down(s0, off);
        s1 += __shfl_down(s1, off);
    }
    if (lane == 0) {
        float l0 = s0 + bvec[0], l1 = s1 + bvec[1];
        float m = fmaxf(l0, l1);
        float lse = m + __logf(__expf(l0 - m) + __expf(l1 - m));
        int orig = perm[bi];
        out[orig * 2 + 0] = l0 - lse;
        out[orig * 2 + 1] = l1 - lse;
    }
}

// ---------------- launch ----------------

extern "C" void kernel_launch(void* const* d_in, const int* in_sizes, int n_in,
                              void* d_out, int out_size, void* d_ws, size_t ws_size,
                              hipStream_t stream)
{
    const int*   x       = (const int*)  d_in[0];
    const int*   x_index = (const int*)  d_in[1];
    const float* emb_t   = (const float*)d_in[2];
    const float* W_ih    = (const float*)d_in[3];
    const float* W_hh    = (const float*)d_in[4];
    const float* b_ih    = (const float*)d_in[5];
    const float* b_hh    = (const float*)d_in[6];
    const float* fc1_w   = (const float*)d_in[7];
    const float* fc1_b   = (const float*)d_in[8];
    const float* fc2_w   = (const float*)d_in[9];
    const float* fc2_b   = (const float*)d_in[10];
    const float* h0      = (const float*)d_in[11];
    const float* c0      = (const float*)d_in[12];
    float* out = (float*)d_out;

    char* p = (char*)d_ws;
    u16*   emb_bf = (u16*)p;   p += (size_t)B_ * T_ * E_ * 2;   // 134 MB
    u16*   wcat   = (u16*)p;   p += (size_t)G4H * KCAT * 2;     // 12.6 MB
    u16*   fc1wbf = (u16*)p;   p += (size_t)M_ * H_ * 2;        // 2 MB
    float* bias   = (float*)p; p += (size_t)G4H * 4;
    u16*   hbuf   = (u16*)p;   p += (size_t)2 * B_ * H_ * 2;    // ping-pong h
    float* c0p    = (float*)p; p += (size_t)B_ * H_ * 4;
    float* hn     = (float*)p; p += (size_t)B_ * H_ * 4;
    u16*   hnbf   = (u16*)p;   p += (size_t)B_ * H_ * 2;
    float* zbuf   = (float*)p; p += (size_t)B_ * M_ * 4;
    int*   perm   = (int*)p;   p += (size_t)B_ * 4;
    int*   sxi    = (int*)p;   p += (size_t)B_ * 4;
    u32*   flags  = (u32*)p;   p += (size_t)16 * 128 * 4;

    sort_rows <<<1,     256, 0, stream>>>(x_index, perm, sxi);
    prep_emb  <<<65536, 256, 0, stream>>>(x, emb_t, perm, emb_bf);
    prep_wcat <<<6144,  256, 0, stream>>>(W_hh, W_ih, wcat);
    prep_fc1w <<<1024,  256, 0, stream>>>(fc1_w, fc1wbf);
    prep_bias <<<16,    256, 0, stream>>>(b_ih, b_hh, bias);
    prep_state<<<1024,  256, 0, stream>>>(h0, c0, perm, hbuf, c0p);
    zero_flags<<<8,     256, 0, stream>>>(flags);

    lstm_persist<<<256, 512, 0, stream>>>(emb_bf, wcat, bias, c0p, sxi,
                                          hbuf, hn, flags);

    hn_convert <<<1024, 256, 0, stream>>>(hn, hnbf);
    fc1_kernel <<<dim3(16, 4), 256, 0, stream>>>(hnbf, fc1wbf, fc1_b, zbuf);
    fc2_softmax<<<256, 64, 0, stream>>>(zbuf, fc2_w, fc2_b, perm, out);
}